// Round 6
// baseline (576.139 us; speedup 1.0000x reference)
//
#include <hip/hip_runtime.h>
#include <hip/hip_bf16.h>
#include <math.h>

typedef __attribute__((ext_vector_type(8))) short bf16x8;
typedef __attribute__((ext_vector_type(8))) unsigned short u16x8;
typedef __attribute__((ext_vector_type(4))) float f32x4;
typedef __attribute__((ext_vector_type(4))) unsigned short u16x4;

__device__ inline unsigned short f2bf(float f) {
    union { float f; unsigned u; } v; v.f = f;
    unsigned r = (v.u + 0x7fff + ((v.u >> 16) & 1)) >> 16;   // RNE
    return (unsigned short)r;
}
__device__ inline float bf2f(unsigned short u) {
    union { unsigned u; float f; } v; v.u = ((unsigned)u) << 16; return v.f;
}

#define GLL16(gp, lp) __builtin_amdgcn_global_load_lds(                      \
    (const __attribute__((address_space(1))) void*)(gp),                     \
    (__attribute__((address_space(3))) void*)(lp), 16, 0, 0)

__device__ inline void block_bar() {
    asm volatile("" ::: "memory");
    __builtin_amdgcn_s_barrier();
    asm volatile("" ::: "memory");
}
#define LGKM0() do {                                             \
    asm volatile("s_waitcnt lgkmcnt(0)" ::: "memory");           \
    __builtin_amdgcn_sched_barrier(0);                           \
} while (0)

// ---------------------------------------------------------------------------
// bf16 MFMA GEMM, 8-phase schedule (T2+T3+T4+T5): BM=256, BK=64, 8 waves 2Mx4N,
// per-wave 128 x (BN/4). Double-buffered LDS; each K-tile = 4 phases, each
// phase stages ONE half-tile of K-tile t+1 via global_load_lds and runs a
// 16-MFMA C-quadrant between raw barriers. Counted vmcnt (never 0 mid-loop):
//   ph1: vmcnt(2*BLD) -> A-half1(t) landed before ph2 reads it
//   ph3: vmcnt(2)     -> B0,B1,A0(t+1) landed before next ph0
// Wave mi-blocks interleaved (row = mi*32 + wr*16 + lk) so A stage-half h is
// consumed only in phases 2h..2h+1. Full (row&7) XOR slot swizzle on stage
// source + ds_read (involution, rule 21) -> conflict-free b128 reads.
// EPI: 0=none 1=+bias 2=+bias+gelu(exact). OUT_BF: bf16 output.
// ---------------------------------------------------------------------------
template<int EPI, int OUT_BF, int BN>
__global__ __launch_bounds__(512) void gemm8(
    const unsigned short* __restrict__ A,
    const unsigned short* __restrict__ Bt,
    const float* __restrict__ bias,
    void* __restrict__ Cout,
    int M, int Nn, int K, int ldc)
{
    constexpr int NF   = BN / 64;          // nj frags per wave (4 or 2)
    constexpr int NG   = NF / 2;           // njs per group
    constexpr int ABYT = 256 * 128;        // A-tile bytes (32 KB)
    constexpr int BBYT = BN * 128;         // B-tile bytes
    constexpr int BUFB = ABYT + BBYT;
    constexpr int BLD  = BN / 128;         // gloads/thread per B half (2 or 1)
    constexpr int P1   = 2 * BLD;
    constexpr int P0   = 2;
    __shared__ unsigned char lds[2 * BUFB];   // 128 KB / 96 KB

    const int tid = threadIdx.x;
    const int w = tid >> 6, lane = tid & 63;
    const int lk = lane & 15, lg = lane >> 4;
    const int wr = w >> 2, wc = w & 3;
    const int nbn = Nn / BN;
    const int nb = gridDim.x;
    int bid = blockIdx.x;
    int swz = (nb & 7) ? bid : (bid & 7) * (nb >> 3) + (bid >> 3);  // XCD swizzle
    const int bm = (swz / nbn) << 8;
    const int bn = (swz % nbn) * BN;

    f32x4 acc[8][NF] = {};
    bf16x8 af[4][2];             // current A half: [mi][kk]
    bf16x8 bg[2][NG][2];         // [group][nj][kk]

    const int NT = K >> 6;

    auto stA = [&](int buf, int half, int kt) {
        #pragma unroll
        for (int i = 0; i < 2; ++i) {
            int s = tid + i * 512;
            int r = s >> 3, cs = (s & 7) ^ (r & 7);
            GLL16(A + (size_t)(bm + half * 128 + r) * K + kt + cs * 8,
                  &lds[buf * BUFB + half * 16384 + s * 16]);
        }
    };
    auto stB = [&](int buf, int half, int kt) {
        #pragma unroll
        for (int i = 0; i < BLD; ++i) {
            int s = tid + i * 512;
            int r = s >> 3, cs = (s & 7) ^ (r & 7);
            GLL16(Bt + (size_t)(bn + half * (BN / 2) + r) * K + kt + cs * 8,
                  &lds[buf * BUFB + ABYT + half * (BBYT / 2) + s * 16]);
        }
    };
    auto rdA = [&](int buf, int haf) {
        #pragma unroll
        for (int mi = 0; mi < 4; ++mi) {
            int row = (haf * 4 + mi) * 32 + wr * 16 + lk;
            #pragma unroll
            for (int kk = 0; kk < 2; ++kk) {
                int sl = (kk * 4 + lg) ^ (row & 7);
                af[mi][kk] = *(const bf16x8*)&lds[buf * BUFB + row * 128 + sl * 16];
            }
        }
    };
    auto rdB = [&](int buf, int g) {
        #pragma unroll
        for (int nj = 0; nj < NG; ++nj) {
            int row = wc * (BN / 4) + (g * NG + nj) * 16 + lk;
            #pragma unroll
            for (int kk = 0; kk < 2; ++kk) {
                int sl = (kk * 4 + lg) ^ (row & 7);
                bg[g][nj][kk] = *(const bf16x8*)&lds[buf * BUFB + ABYT + row * 128 + sl * 16];
            }
        }
    };
    auto mfmaq = [&](int haf, int g) {
        __builtin_amdgcn_s_setprio(1);
        #pragma unroll
        for (int mi = 0; mi < 4; ++mi)
            #pragma unroll
            for (int nj = 0; nj < NG; ++nj)
                #pragma unroll
                for (int kk = 0; kk < 2; ++kk)
                    acc[haf * 4 + mi][g * NG + nj] =
                        __builtin_amdgcn_mfma_f32_16x16x32_bf16(
                            af[mi][kk], bg[g][nj][kk],
                            acc[haf * 4 + mi][g * NG + nj], 0, 0, 0);
        __builtin_amdgcn_s_setprio(0);
    };

    auto ktile = [&](int t, int buf) {
        const bool stg = (t + 1) < NT;
        const int kn = (t + 1) << 6;
        // ---- ph0: quad (A0, B-group0)
        rdA(buf, 0); rdB(buf, 0);
        if (stg) stB(buf ^ 1, 0, kn);
        block_bar(); LGKM0();
        mfmaq(0, 0);
        block_bar();
        // ---- ph1: quad (A0, B-group1)
        rdB(buf, 1);
        if (stg) {
            stB(buf ^ 1, 1, kn);
            asm volatile("s_waitcnt vmcnt(%0)" :: "i"(P1) : "memory");
        } else {
            asm volatile("s_waitcnt vmcnt(0)" ::: "memory");
        }
        block_bar(); LGKM0();
        mfmaq(0, 1);
        block_bar();
        // ---- ph2: quad (A1, B-group0)
        rdA(buf, 1);
        if (stg) stA(buf ^ 1, 0, kn);
        block_bar(); LGKM0();
        mfmaq(1, 0);
        block_bar();
        // ---- ph3: quad (A1, B-group1)
        if (stg) {
            stA(buf ^ 1, 1, kn);
            asm volatile("s_waitcnt vmcnt(%0)" :: "i"(P0) : "memory");
        }
        block_bar(); LGKM0();
        mfmaq(1, 1);
        block_bar();
    };

    // prologue: stage K-tile 0 (order B0,B1,A0,A1), wait all but A1, barrier
    stB(0, 0, 0); stB(0, 1, 0); stA(0, 0, 0); stA(0, 1, 0);
    asm volatile("s_waitcnt vmcnt(%0)" :: "i"(P0) : "memory");
    block_bar();

    for (int t = 0; t < NT; t += 2) {
        ktile(t, 0);
        ktile(t + 1, 1);
    }

    #pragma unroll
    for (int mi = 0; mi < 8; ++mi) {
        int row = bm + mi * 32 + wr * 16 + lg * 4;
        #pragma unroll
        for (int nj = 0; nj < NF; ++nj) {
            int col = bn + wc * (BN / 4) + nj * 16 + lk;
            #pragma unroll
            for (int r = 0; r < 4; ++r) {
                float v = acc[mi][nj][r];
                if (EPI >= 1) v += bias[col];
                if (EPI == 2) v = 0.5f * v * (1.0f + erff(v * 0.7071067811865475f));
                if (OUT_BF)
                    ((unsigned short*)Cout)[(size_t)(row + r) * ldc + col] = f2bf(v);
                else
                    ((float*)Cout)[(size_t)(row + r) * ldc + col] = v;
            }
        }
    }
}

// ---------------------------------------------------------------------------
// fp32 -> bf16 flat convert, 4 elems/thread
// ---------------------------------------------------------------------------
__global__ __launch_bounds__(256) void cvt_bf16(
    const float* __restrict__ src, unsigned short* __restrict__ dst, int n)
{
    int i = (blockIdx.x * 256 + threadIdx.x) * 4;
    if (i < n) {
        float4 v = *(const float4*)(src + i);
        u16x4 o = { f2bf(v.x), f2bf(v.y), f2bf(v.z), f2bf(v.w) };
        *(u16x4*)(dst + i) = o;
    }
}

// ---------------------------------------------------------------------------
// transpose + convert: src [R][Cc] f32 -> dst [Cc][R] bf16 (for B^T weights)
// ---------------------------------------------------------------------------
__global__ __launch_bounds__(256) void transpose_cvt(
    const float* __restrict__ src, unsigned short* __restrict__ dst, int R, int Cc)
{
    __shared__ float t[32][33];
    const int bc = blockIdx.x * 32, br = blockIdx.y * 32;
    const int tx = threadIdx.x & 31, ty = threadIdx.x >> 5;
    #pragma unroll
    for (int i = 0; i < 4; ++i)
        t[ty + i * 8][tx] = src[(size_t)(br + ty + i * 8) * Cc + bc + tx];
    __syncthreads();
    #pragma unroll
    for (int i = 0; i < 4; ++i)
        dst[(size_t)(bc + ty + i * 8) * R + br + tx] = f2bf(t[tx][ty + i * 8]);
}

// ---------------------------------------------------------------------------
// drofe on bf16 QK [M][2048] -> rotated bf16 Q [M][1024] (scale folded), K.
// ---------------------------------------------------------------------------
__global__ __launch_bounds__(256) void drofe_bf(
    const unsigned short* __restrict__ QK, unsigned short* __restrict__ Qo,
    unsigned short* __restrict__ Ko,
    const float* __restrict__ freqband, const float* __restrict__ demo, int N)
{
    const float PI_F = 3.14159265358979323846f;
    int idx = blockIdx.x * 256 + threadIdx.x;
    int col2 = idx & 511;
    int row  = idx >> 9;
    int n = row & (N - 1), b = row >> 10;
    int i  = col2 & 31;
    int ii = (i < 16) ? i : i - 16;
    float fb = (i < 16) ? freqband[n * 2 + 0] : freqband[n * 2 + 1];
    float freq = (1.0f + (float)ii * (4.0f / 15.0f)) * PI_F;
    float ang = fb * freq;
    float cv = cosf(ang), sv = sinf(ang);
    float ca = cv * demo[b * 2 + 0];
    float sg = sv * demo[b * 2 + 1];
    const unsigned* qk = (const unsigned*)(QK + (size_t)row * 2048);
    unsigned qu = qk[col2], ku = qk[512 + col2];
    float qe = bf2f((unsigned short)qu), qo_ = bf2f((unsigned short)(qu >> 16));
    float ke = bf2f((unsigned short)ku), ko_ = bf2f((unsigned short)(ku >> 16));
    const float s8 = 0.125f;
    unsigned qres = (unsigned)f2bf((qe * ca - qo_ * sg) * s8)
                  | ((unsigned)f2bf((qo_ * ca + qe * sg) * s8) << 16);
    unsigned kres = (unsigned)f2bf(ke * ca - ko_ * sg)
                  | ((unsigned)f2bf(ko_ * ca + ke * sg) << 16);
    ((unsigned*)Qo)[(size_t)row * 512 + col2] = qres;
    ((unsigned*)Ko)[(size_t)row * 512 + col2] = kres;
}

// ---------------------------------------------------------------------------
// Flash attention, bf16 in/out, MFMA 16x16x32, fp32 accum. (round-4 verified)
// ---------------------------------------------------------------------------
__global__ __launch_bounds__(256) void attn_mfma(
    const unsigned short* __restrict__ Q, const unsigned short* __restrict__ K,
    const unsigned short* __restrict__ V, unsigned short* __restrict__ O,
    int B, int H, int N)
{
    __shared__ unsigned short Ks[64 * 64];
    __shared__ unsigned short Vt[64 * 72];
    __shared__ unsigned short Ps[4][16 * 72];

    const int bi = blockIdx.x;
    const int bh = (bi & 7) + 8 * ((bi >> 3) & 15);
    const int q0 = (bi >> 7) * 64;
    const int b = bh >> 4, h = bh & 15;
    const int tid = threadIdx.x;
    const int w = tid >> 6, lane = tid & 63;
    const int lg = lane >> 4, lk = lane & 15;

    bf16x8 qf[2];
    {
        const unsigned short* qrow = Q + (size_t)(b * N + q0 + w * 16 + lk) * 1024 + h * 64;
        qf[0] = *(const bf16x8*)(qrow + lg * 8);
        qf[1] = *(const bf16x8*)(qrow + 32 + lg * 8);
    }

    f32x4 o[4] = {};
    float mrow[4], lrow[4];
    #pragma unroll
    for (int r = 0; r < 4; ++r) { mrow[r] = -INFINITY; lrow[r] = 0.f; }

    for (int t0 = 0; t0 < N; t0 += 64) {
        const size_t kvbase = (size_t)(b * N + t0) * 1024 + h * 64;
        #pragma unroll
        for (int it = 0; it < 2; ++it) {
            int s = it * 256 + tid;
            int row = s >> 3, cb = (s & 7) << 4;
            int dby = cb ^ ((row & 7) << 4);
            GLL16(K + kvbase + (size_t)row * 1024 + (dby >> 1), &Ks[s * 8]);
        }
        {
            int c = tid >> 5, k0 = (tid & 31) * 2;
            const unsigned short* vp = V + kvbase + (size_t)k0 * 1024 + c * 8;
            u16x8 va = *(const u16x8*)vp;
            u16x8 vb = *(const u16x8*)(vp + 1024);
            #pragma unroll
            for (int j = 0; j < 8; ++j) {
                unsigned val = (unsigned)va[j] | ((unsigned)vb[j] << 16);
                *(unsigned*)&Vt[(c * 8 + j) * 72 + k0] = val;
            }
        }
        __syncthreads();

        f32x4 s4[4];
        #pragma unroll
        for (int sub = 0; sub < 4; ++sub) {
            f32x4 acc = {0.f, 0.f, 0.f, 0.f};
            #pragma unroll
            for (int kh = 0; kh < 2; ++kh) {
                int cc = (kh * 64 + lg * 16) ^ ((lk & 7) << 4);
                bf16x8 kf = *(const bf16x8*)&Ks[(sub * 16 + lk) * 64 + (cc >> 1)];
                acc = __builtin_amdgcn_mfma_f32_16x16x32_bf16(qf[kh], kf, acc, 0, 0, 0);
            }
            s4[sub] = acc;
        }

        #pragma unroll
        for (int r = 0; r < 4; ++r) {
            float tm = fmaxf(fmaxf(s4[0][r], s4[1][r]), fmaxf(s4[2][r], s4[3][r]));
            #pragma unroll
            for (int msk = 1; msk < 16; msk <<= 1) tm = fmaxf(tm, __shfl_xor(tm, msk));
            float mn = fmaxf(mrow[r], tm);
            float corr = __expf(mrow[r] - mn);
            mrow[r] = mn;
            float psum = 0.f;
            unsigned short pb[4];
            #pragma unroll
            for (int sub = 0; sub < 4; ++sub) {
                float p = __expf(s4[sub][r] - mn);
                psum += p;
                pb[sub] = f2bf(p);
            }
            #pragma unroll
            for (int msk = 1; msk < 16; msk <<= 1) psum += __shfl_xor(psum, msk);
            lrow[r] = lrow[r] * corr + psum;
            #pragma unroll
            for (int ds = 0; ds < 4; ++ds) o[ds][r] *= corr;
            int q = lg * 4 + r;
            #pragma unroll
            for (int sub = 0; sub < 4; ++sub)
                Ps[w][q * 72 + sub * 16 + lk] = pb[sub];
        }
        asm volatile("s_waitcnt lgkmcnt(0)" ::: "memory");

        #pragma unroll
        for (int kh = 0; kh < 2; ++kh) {
            bf16x8 pf = *(const bf16x8*)&Ps[w][lk * 72 + kh * 32 + lg * 8];
            #pragma unroll
            for (int ds = 0; ds < 4; ++ds) {
                bf16x8 vf = *(const bf16x8*)&Vt[(ds * 16 + lk) * 72 + kh * 32 + lg * 8];
                o[ds] = __builtin_amdgcn_mfma_f32_16x16x32_bf16(pf, vf, o[ds], 0, 0, 0);
            }
        }
        __syncthreads();
    }

    #pragma unroll
    for (int ds = 0; ds < 4; ++ds)
        #pragma unroll
        for (int r = 0; r < 4; ++r) {
            int q = lg * 4 + r;
            O[(size_t)(b * N + q0 + w * 16 + q) * 1024 + h * 64 + ds * 16 + lk] =
                f2bf(o[ds][r] / lrow[r]);
        }
}

// ---------------------------------------------------------------------------
// Fused residual + LayerNorm: out = LN(x + gamma*y) * w + b  (+ optional bf16)
// ---------------------------------------------------------------------------
__global__ __launch_bounds__(256) void ln_res_kernel(
    const float* __restrict__ x, const float* __restrict__ y,
    const float* __restrict__ gamma, const float* __restrict__ w,
    const float* __restrict__ bia, float* __restrict__ out,
    unsigned short* __restrict__ out_bf, int C)
{
    const int row = blockIdx.x;
    __shared__ float buf[1024];
    __shared__ float red[8];
    const size_t base = (size_t)row * C;
    float s = 0.f, ss = 0.f;
    for (int c = threadIdx.x; c < C; c += 256) {
        float v = x[base + c] + gamma[c] * y[base + c];
        buf[c] = v; s += v; ss += v * v;
    }
    #pragma unroll
    for (int msk = 1; msk < 64; msk <<= 1) { s += __shfl_xor(s, msk); ss += __shfl_xor(ss, msk); }
    int wv = threadIdx.x >> 6, lane = threadIdx.x & 63;
    if (lane == 0) { red[wv * 2] = s; red[wv * 2 + 1] = ss; }
    __syncthreads();
    if (threadIdx.x == 0) {
        float S = 0.f, SS = 0.f;
        #pragma unroll
        for (int i = 0; i < 4; ++i) { S += red[2 * i]; SS += red[2 * i + 1]; }
        red[0] = S; red[1] = SS;
    }
    __syncthreads();
    float mu = red[0] / C;
    float var = red[1] / C - mu * mu;
    float rstd = rsqrtf(var + 1e-5f);
    for (int c = threadIdx.x; c < C; c += 256) {
        float v = (buf[c] - mu) * rstd * w[c] + bia[c];
        out[base + c] = v;
        if (out_bf) out_bf[base + c] = f2bf(v);
    }
}

// ---------------------------------------------------------------------------
extern "C" void kernel_launch(void* const* d_in, const int* in_sizes, int n_in,
                              void* d_out, int out_size, void* d_ws, size_t ws_size,
                              hipStream_t stream)
{
    const float* x      = (const float*)d_in[0];
    const float* demo   = (const float*)d_in[1];
    const float* expl   = (const float*)d_in[2];
    const float* fb     = (const float*)d_in[3];
    const float* w_qkv  = (const float*)d_in[4];
    const float* w_proj = (const float*)d_in[5];
    const float* b_proj = (const float*)d_in[6];
    const float* gamma1 = (const float*)d_in[7];
    const float* gamma2 = (const float*)d_in[8];
    const float* ln1_w  = (const float*)d_in[9];
    const float* ln1_b  = (const float*)d_in[10];
    const float* ln2_w  = (const float*)d_in[11];
    const float* ln2_b  = (const float*)d_in[12];
    const float* w1     = (const float*)d_in[13];
    const float* b1     = (const float*)d_in[14];
    const float* w2     = (const float*)d_in[15];
    const float* b2     = (const float*)d_in[16];
    float* out = (float*)d_out;

    const int B = 8, N = 1024, C = 1024, F = 4096, H = 16;
    const int M = B * N;                        // 8192
    const size_t Mi = 1048576;

    float* ws = (float*)d_ws;
    unsigned short* QKbf = (unsigned short*)ws;              // M x 2048 bf16
    unsigned short* Obf  = (unsigned short*)ws;              // M x 1024 bf16
    float*          H2   = ws;                               // M x 1024 f32
    unsigned short* Qbf  = (unsigned short*)(ws + 8 * Mi);   // M x 1024 bf16
    unsigned short* Kbf  = (unsigned short*)(ws + 12 * Mi);
    unsigned short* Vbf  = (unsigned short*)(ws + 16 * Mi);
    unsigned short* Hid  = (unsigned short*)(ws + 8 * Mi);   // M x 4096 bf16
    unsigned short* Ebf  = (unsigned short*)(ws + 24 * Mi);
    unsigned short* Xbf  = (unsigned short*)(ws + 28 * Mi);
    float*          Pb   = ws + 24 * Mi;                     // M x 1024 f32
    float*          X1   = ws + 32 * Mi;                     // M x 1024 f32
    unsigned short* X1bf = (unsigned short*)(ws + 40 * Mi);
    unsigned short* Wt   = (unsigned short*)(ws + 44 * Mi);
    unsigned short* wqkvT  = Wt;                             // [3072][1024]
    unsigned short* wprojT = Wt + (size_t)3145728;           // [1024][1024]
    unsigned short* w1T    = wprojT + (size_t)1048576;       // [4096][1024]
    unsigned short* w2T    = w1T + (size_t)4194304;          // [1024][4096]

    dim3 blk(256);
    dim3 blk5(512);
    const int MC = M * C;

    hipLaunchKernelGGL(cvt_bf16, dim3(MC / 1024), blk, 0, stream, expl, Ebf, MC);
    hipLaunchKernelGGL(cvt_bf16, dim3(MC / 1024), blk, 0, stream, x, Xbf, MC);
    hipLaunchKernelGGL(transpose_cvt, dim3(96, 32), blk, 0, stream, w_qkv, wqkvT, C, 3 * C);
    hipLaunchKernelGGL(transpose_cvt, dim3(32, 32), blk, 0, stream, w_proj, wprojT, C, C);
    hipLaunchKernelGGL(transpose_cvt, dim3(128, 32), blk, 0, stream, w1, w1T, C, F);
    hipLaunchKernelGGL(transpose_cvt, dim3(32, 128), blk, 0, stream, w2, w2T, F, C);

    // QK projection (explanation) -> bf16; V projection (x) -> bf16
    hipLaunchKernelGGL((gemm8<0,1,256>), dim3(256), blk5, 0, stream, Ebf, wqkvT, (const float*)nullptr, (void*)QKbf, M, 2048, C, 2048);
    hipLaunchKernelGGL((gemm8<0,1,128>), dim3(256), blk5, 0, stream, Xbf, wqkvT + (size_t)2048 * 1024, (const float*)nullptr, (void*)Vbf, M, 1024, C, 1024);

    // drofe: bf16 QK -> rotated bf16 Q (scaled), K
    hipLaunchKernelGGL(drofe_bf, dim3(M * 512 / 256), blk, 0, stream, QKbf, Qbf, Kbf, fb, demo, N);

    // attention -> bf16 O
    hipLaunchKernelGGL(attn_mfma, dim3(B * H * (N / 64)), blk, 0, stream, Qbf, Kbf, Vbf, Obf, B, H, N);

    // output projection
    hipLaunchKernelGGL((gemm8<1,0,128>), dim3(256), blk5, 0, stream, Obf, wprojT, b_proj, (void*)Pb, M, 1024, C, 1024);

    // residual + LN1 (f32 + bf16)
    hipLaunchKernelGGL(ln_res_kernel, dim3(M), blk, 0, stream, x, Pb, gamma1, ln1_w, ln1_b, X1, X1bf, C);

    // MLP
    hipLaunchKernelGGL((gemm8<2,1,256>), dim3(512), blk5, 0, stream, X1bf, w1T, b1, (void*)Hid, M, F, C, F);
    hipLaunchKernelGGL((gemm8<1,0,128>), dim3(256), blk5, 0, stream, Hid, w2T, b2, (void*)H2, M, 1024, F, 1024);

    // residual + LN2 -> out
    hipLaunchKernelGGL(ln_res_kernel, dim3(M), blk, 0, stream, X1, H2, gamma2, ln2_w, ln2_b, out, (unsigned short*)nullptr, C);
}

// Round 7
// 480.024 us; speedup vs baseline: 1.2002x; 1.2002x over previous
//
#include <hip/hip_runtime.h>
#include <hip/hip_bf16.h>
#include <math.h>

typedef __attribute__((ext_vector_type(8))) short bf16x8;
typedef __attribute__((ext_vector_type(8))) unsigned short u16x8;
typedef __attribute__((ext_vector_type(4))) float f32x4;
typedef __attribute__((ext_vector_type(4))) unsigned short u16x4;

__device__ inline unsigned short f2bf(float f) {
    union { float f; unsigned u; } v; v.f = f;
    unsigned r = (v.u + 0x7fff + ((v.u >> 16) & 1)) >> 16;   // RNE
    return (unsigned short)r;
}
__device__ inline float bf2f(unsigned short u) {
    union { unsigned u; float f; } v; v.u = ((unsigned)u) << 16; return v.f;
}

#define GLL16(gp, lp) __builtin_amdgcn_global_load_lds(                      \
    (const __attribute__((address_space(1))) void*)(gp),                     \
    (__attribute__((address_space(3))) void*)(lp), 16, 0, 0)

// ---------------------------------------------------------------------------
// bf16 MFMA GEMM, m97 structure + BK=64 + XOR swizzle:
// 128x128 tile, 4 waves (2x2), per-wave 64x64 = 4x4 frags of 16x16x32.
// Single-buffered 32KB LDS -> 4-5 blocks/CU; barrier drain covered by
// implicit multi-block overlap (m114). LDS rows 128B (8 x 16B slots);
// stage source chunk cs = c ^ (row&7), read slot (kk*4+lg) ^ (row&7)
// (involution, rule 21) -> conflict-free ds_read_b128 (verified r5/r6).
// EPI: 0=none 1=+bias 2=+bias+gelu(exact). OUT_BF: bf16 output.
// ---------------------------------------------------------------------------
template<int EPI, int OUT_BF>
__global__ __launch_bounds__(256) void gemm97(
    const unsigned short* __restrict__ A,
    const unsigned short* __restrict__ Bt,
    const float* __restrict__ bias,
    void* __restrict__ Cout,
    int M, int Nn, int K, int ldc)
{
    __shared__ unsigned char lds[32768];        // A 16KB ++ B 16KB
    const int tid = threadIdx.x;
    const int w = tid >> 6, lane = tid & 63;
    const int lk = lane & 15, lg = lane >> 4;
    const int wr = w >> 1, wc = w & 1;
    const int nbn = Nn >> 7;
    const int nb = gridDim.x;
    int bid = blockIdx.x;
    int swz = (nb & 7) ? bid : (bid & 7) * (nb >> 3) + (bid >> 3);  // XCD swizzle
    const int bm = (swz / nbn) << 7, bn = (swz % nbn) << 7;

    f32x4 acc[4][4] = {};

    for (int k0 = 0; k0 < K; k0 += 64) {
        #pragma unroll
        for (int i = 0; i < 8; ++i) {           // 2048 slots of 16B
            int s = tid + i * 256;
            int r = s >> 3, c = s & 7;
            int cs = c ^ (r & 7);
            const unsigned short* gp = (r < 128)
                ? A  + (size_t)(bm + r) * K + k0 + cs * 8
                : Bt + (size_t)(bn + (r - 128)) * K + k0 + cs * 8;
            GLL16(gp, &lds[s * 16]);
        }
        __syncthreads();                        // compiler drains vmcnt

        #pragma unroll
        for (int kk = 0; kk < 2; ++kk) {
            bf16x8 af[4], bfr[4];
            #pragma unroll
            for (int m = 0; m < 4; ++m) {
                int row = wr * 64 + m * 16 + lk;
                af[m] = *(const bf16x8*)&lds[row * 128 + (((kk * 4 + lg) ^ (row & 7)) << 4)];
            }
            #pragma unroll
            for (int n = 0; n < 4; ++n) {
                int row = wc * 64 + n * 16 + lk;
                bfr[n] = *(const bf16x8*)&lds[16384 + row * 128 + (((kk * 4 + lg) ^ (row & 7)) << 4)];
            }
            #pragma unroll
            for (int m = 0; m < 4; ++m)
                #pragma unroll
                for (int n = 0; n < 4; ++n)
                    acc[m][n] = __builtin_amdgcn_mfma_f32_16x16x32_bf16(af[m], bfr[n], acc[m][n], 0, 0, 0);
        }
        __syncthreads();
    }

    #pragma unroll
    for (int m = 0; m < 4; ++m) {
        int row = bm + wr * 64 + m * 16 + lg * 4;
        #pragma unroll
        for (int n = 0; n < 4; ++n) {
            int col = bn + wc * 64 + n * 16 + lk;
            #pragma unroll
            for (int r = 0; r < 4; ++r) {
                float v = acc[m][n][r];
                if (EPI >= 1) v += bias[col];
                if (EPI == 2) v = 0.5f * v * (1.0f + erff(v * 0.7071067811865475f));
                if (OUT_BF)
                    ((unsigned short*)Cout)[(size_t)(row + r) * ldc + col] = f2bf(v);
                else
                    ((float*)Cout)[(size_t)(row + r) * ldc + col] = v;
            }
        }
    }
}

// ---------------------------------------------------------------------------
// fp32 -> bf16 flat convert, 4 elems/thread
// ---------------------------------------------------------------------------
__global__ __launch_bounds__(256) void cvt_bf16(
    const float* __restrict__ src, unsigned short* __restrict__ dst, int n)
{
    int i = (blockIdx.x * 256 + threadIdx.x) * 4;
    if (i < n) {
        float4 v = *(const float4*)(src + i);
        u16x4 o = { f2bf(v.x), f2bf(v.y), f2bf(v.z), f2bf(v.w) };
        *(u16x4*)(dst + i) = o;
    }
}

// ---------------------------------------------------------------------------
// transpose + convert: src [R][Cc] f32 -> dst [Cc][R] bf16 (for B^T weights)
// ---------------------------------------------------------------------------
__global__ __launch_bounds__(256) void transpose_cvt(
    const float* __restrict__ src, unsigned short* __restrict__ dst, int R, int Cc)
{
    __shared__ float t[32][33];
    const int bc = blockIdx.x * 32, br = blockIdx.y * 32;
    const int tx = threadIdx.x & 31, ty = threadIdx.x >> 5;
    #pragma unroll
    for (int i = 0; i < 4; ++i)
        t[ty + i * 8][tx] = src[(size_t)(br + ty + i * 8) * Cc + bc + tx];
    __syncthreads();
    #pragma unroll
    for (int i = 0; i < 4; ++i)
        dst[(size_t)(bc + ty + i * 8) * R + br + tx] = f2bf(t[tx][ty + i * 8]);
}

// ---------------------------------------------------------------------------
// drofe on bf16 QK [M][2048] -> rotated bf16 Q [M][1024] (scale folded), K.
// ---------------------------------------------------------------------------
__global__ __launch_bounds__(256) void drofe_bf(
    const unsigned short* __restrict__ QK, unsigned short* __restrict__ Qo,
    unsigned short* __restrict__ Ko,
    const float* __restrict__ freqband, const float* __restrict__ demo, int N)
{
    const float PI_F = 3.14159265358979323846f;
    int idx = blockIdx.x * 256 + threadIdx.x;
    int col2 = idx & 511;
    int row  = idx >> 9;
    int n = row & (N - 1), b = row >> 10;
    int i  = col2 & 31;
    int ii = (i < 16) ? i : i - 16;
    float fb = (i < 16) ? freqband[n * 2 + 0] : freqband[n * 2 + 1];
    float freq = (1.0f + (float)ii * (4.0f / 15.0f)) * PI_F;
    float ang = fb * freq;
    float cv = cosf(ang), sv = sinf(ang);
    float ca = cv * demo[b * 2 + 0];
    float sg = sv * demo[b * 2 + 1];
    const unsigned* qk = (const unsigned*)(QK + (size_t)row * 2048);
    unsigned qu = qk[col2], ku = qk[512 + col2];
    float qe = bf2f((unsigned short)qu), qo_ = bf2f((unsigned short)(qu >> 16));
    float ke = bf2f((unsigned short)ku), ko_ = bf2f((unsigned short)(ku >> 16));
    const float s8 = 0.125f;
    unsigned qres = (unsigned)f2bf((qe * ca - qo_ * sg) * s8)
                  | ((unsigned)f2bf((qo_ * ca + qe * sg) * s8) << 16);
    unsigned kres = (unsigned)f2bf(ke * ca - ko_ * sg)
                  | ((unsigned)f2bf(ko_ * ca + ke * sg) << 16);
    ((unsigned*)Qo)[(size_t)row * 512 + col2] = qres;
    ((unsigned*)Ko)[(size_t)row * 512 + col2] = kres;
}

// ---------------------------------------------------------------------------
// Flash attention, bf16 in/out, MFMA 16x16x32, fp32 accum. (round-4 verified)
// ---------------------------------------------------------------------------
__global__ __launch_bounds__(256) void attn_mfma(
    const unsigned short* __restrict__ Q, const unsigned short* __restrict__ K,
    const unsigned short* __restrict__ V, unsigned short* __restrict__ O,
    int B, int H, int N)
{
    __shared__ unsigned short Ks[64 * 64];
    __shared__ unsigned short Vt[64 * 72];
    __shared__ unsigned short Ps[4][16 * 72];

    const int bi = blockIdx.x;
    const int bh = (bi & 7) + 8 * ((bi >> 3) & 15);
    const int q0 = (bi >> 7) * 64;
    const int b = bh >> 4, h = bh & 15;
    const int tid = threadIdx.x;
    const int w = tid >> 6, lane = tid & 63;
    const int lg = lane >> 4, lk = lane & 15;

    bf16x8 qf[2];
    {
        const unsigned short* qrow = Q + (size_t)(b * N + q0 + w * 16 + lk) * 1024 + h * 64;
        qf[0] = *(const bf16x8*)(qrow + lg * 8);
        qf[1] = *(const bf16x8*)(qrow + 32 + lg * 8);
    }

    f32x4 o[4] = {};
    float mrow[4], lrow[4];
    #pragma unroll
    for (int r = 0; r < 4; ++r) { mrow[r] = -INFINITY; lrow[r] = 0.f; }

    for (int t0 = 0; t0 < N; t0 += 64) {
        const size_t kvbase = (size_t)(b * N + t0) * 1024 + h * 64;
        #pragma unroll
        for (int it = 0; it < 2; ++it) {
            int s = it * 256 + tid;
            int row = s >> 3, cb = (s & 7) << 4;
            int dby = cb ^ ((row & 7) << 4);
            GLL16(K + kvbase + (size_t)row * 1024 + (dby >> 1), &Ks[s * 8]);
        }
        {
            int c = tid >> 5, k0 = (tid & 31) * 2;
            const unsigned short* vp = V + kvbase + (size_t)k0 * 1024 + c * 8;
            u16x8 va = *(const u16x8*)vp;
            u16x8 vb = *(const u16x8*)(vp + 1024);
            #pragma unroll
            for (int j = 0; j < 8; ++j) {
                unsigned val = (unsigned)va[j] | ((unsigned)vb[j] << 16);
                *(unsigned*)&Vt[(c * 8 + j) * 72 + k0] = val;
            }
        }
        __syncthreads();

        f32x4 s4[4];
        #pragma unroll
        for (int sub = 0; sub < 4; ++sub) {
            f32x4 acc = {0.f, 0.f, 0.f, 0.f};
            #pragma unroll
            for (int kh = 0; kh < 2; ++kh) {
                int cc = (kh * 64 + lg * 16) ^ ((lk & 7) << 4);
                bf16x8 kf = *(const bf16x8*)&Ks[(sub * 16 + lk) * 64 + (cc >> 1)];
                acc = __builtin_amdgcn_mfma_f32_16x16x32_bf16(qf[kh], kf, acc, 0, 0, 0);
            }
            s4[sub] = acc;
        }

        #pragma unroll
        for (int r = 0; r < 4; ++r) {
            float tm = fmaxf(fmaxf(s4[0][r], s4[1][r]), fmaxf(s4[2][r], s4[3][r]));
            #pragma unroll
            for (int msk = 1; msk < 16; msk <<= 1) tm = fmaxf(tm, __shfl_xor(tm, msk));
            float mn = fmaxf(mrow[r], tm);
            float corr = __expf(mrow[r] - mn);
            mrow[r] = mn;
            float psum = 0.f;
            unsigned short pb[4];
            #pragma unroll
            for (int sub = 0; sub < 4; ++sub) {
                float p = __expf(s4[sub][r] - mn);
                psum += p;
                pb[sub] = f2bf(p);
            }
            #pragma unroll
            for (int msk = 1; msk < 16; msk <<= 1) psum += __shfl_xor(psum, msk);
            lrow[r] = lrow[r] * corr + psum;
            #pragma unroll
            for (int ds = 0; ds < 4; ++ds) o[ds][r] *= corr;
            int q = lg * 4 + r;
            #pragma unroll
            for (int sub = 0; sub < 4; ++sub)
                Ps[w][q * 72 + sub * 16 + lk] = pb[sub];
        }
        asm volatile("s_waitcnt lgkmcnt(0)" ::: "memory");

        #pragma unroll
        for (int kh = 0; kh < 2; ++kh) {
            bf16x8 pf = *(const bf16x8*)&Ps[w][lk * 72 + kh * 32 + lg * 8];
            #pragma unroll
            for (int ds = 0; ds < 4; ++ds) {
                bf16x8 vf = *(const bf16x8*)&Vt[(ds * 16 + lk) * 72 + kh * 32 + lg * 8];
                o[ds] = __builtin_amdgcn_mfma_f32_16x16x32_bf16(pf, vf, o[ds], 0, 0, 0);
            }
        }
        __syncthreads();
    }

    #pragma unroll
    for (int ds = 0; ds < 4; ++ds)
        #pragma unroll
        for (int r = 0; r < 4; ++r) {
            int q = lg * 4 + r;
            O[(size_t)(b * N + q0 + w * 16 + q) * 1024 + h * 64 + ds * 16 + lk] =
                f2bf(o[ds][r] / lrow[r]);
        }
}

// ---------------------------------------------------------------------------
// Fused residual + LayerNorm: out = LN(x + gamma*y) * w + b  (+ optional bf16)
// ---------------------------------------------------------------------------
__global__ __launch_bounds__(256) void ln_res_kernel(
    const float* __restrict__ x, const float* __restrict__ y,
    const float* __restrict__ gamma, const float* __restrict__ w,
    const float* __restrict__ bia, float* __restrict__ out,
    unsigned short* __restrict__ out_bf, int C)
{
    const int row = blockIdx.x;
    __shared__ float buf[1024];
    __shared__ float red[8];
    const size_t base = (size_t)row * C;
    float s = 0.f, ss = 0.f;
    for (int c = threadIdx.x; c < C; c += 256) {
        float v = x[base + c] + gamma[c] * y[base + c];
        buf[c] = v; s += v; ss += v * v;
    }
    #pragma unroll
    for (int msk = 1; msk < 64; msk <<= 1) { s += __shfl_xor(s, msk); ss += __shfl_xor(ss, msk); }
    int wv = threadIdx.x >> 6, lane = threadIdx.x & 63;
    if (lane == 0) { red[wv * 2] = s; red[wv * 2 + 1] = ss; }
    __syncthreads();
    if (threadIdx.x == 0) {
        float S = 0.f, SS = 0.f;
        #pragma unroll
        for (int i = 0; i < 4; ++i) { S += red[2 * i]; SS += red[2 * i + 1]; }
        red[0] = S; red[1] = SS;
    }
    __syncthreads();
    float mu = red[0] / C;
    float var = red[1] / C - mu * mu;
    float rstd = rsqrtf(var + 1e-5f);
    for (int c = threadIdx.x; c < C; c += 256) {
        float v = (buf[c] - mu) * rstd * w[c] + bia[c];
        out[base + c] = v;
        if (out_bf) out_bf[base + c] = f2bf(v);
    }
}

// ---------------------------------------------------------------------------
extern "C" void kernel_launch(void* const* d_in, const int* in_sizes, int n_in,
                              void* d_out, int out_size, void* d_ws, size_t ws_size,
                              hipStream_t stream)
{
    const float* x      = (const float*)d_in[0];
    const float* demo   = (const float*)d_in[1];
    const float* expl   = (const float*)d_in[2];
    const float* fb     = (const float*)d_in[3];
    const float* w_qkv  = (const float*)d_in[4];
    const float* w_proj = (const float*)d_in[5];
    const float* b_proj = (const float*)d_in[6];
    const float* gamma1 = (const float*)d_in[7];
    const float* gamma2 = (const float*)d_in[8];
    const float* ln1_w  = (const float*)d_in[9];
    const float* ln1_b  = (const float*)d_in[10];
    const float* ln2_w  = (const float*)d_in[11];
    const float* ln2_b  = (const float*)d_in[12];
    const float* w1     = (const float*)d_in[13];
    const float* b1     = (const float*)d_in[14];
    const float* w2     = (const float*)d_in[15];
    const float* b2     = (const float*)d_in[16];
    float* out = (float*)d_out;

    const int B = 8, N = 1024, C = 1024, F = 4096, H = 16;
    const int M = B * N;                        // 8192
    const size_t Mi = 1048576;

    float* ws = (float*)d_ws;
    unsigned short* QKbf = (unsigned short*)ws;              // M x 2048 bf16
    unsigned short* Obf  = (unsigned short*)ws;              // M x 1024 bf16
    float*          H2   = ws;                               // M x 1024 f32
    unsigned short* Qbf  = (unsigned short*)(ws + 8 * Mi);   // M x 1024 bf16
    unsigned short* Kbf  = (unsigned short*)(ws + 12 * Mi);
    unsigned short* Vbf  = (unsigned short*)(ws + 16 * Mi);
    unsigned short* Hid  = (unsigned short*)(ws + 8 * Mi);   // M x 4096 bf16
    unsigned short* Ebf  = (unsigned short*)(ws + 24 * Mi);
    unsigned short* Xbf  = (unsigned short*)(ws + 28 * Mi);
    float*          Pb   = ws + 24 * Mi;                     // M x 1024 f32
    float*          X1   = ws + 32 * Mi;                     // M x 1024 f32
    unsigned short* X1bf = (unsigned short*)(ws + 40 * Mi);
    unsigned short* Wt   = (unsigned short*)(ws + 44 * Mi);
    unsigned short* wqkvT  = Wt;                             // [3072][1024]
    unsigned short* wprojT = Wt + (size_t)3145728;           // [1024][1024]
    unsigned short* w1T    = wprojT + (size_t)1048576;       // [4096][1024]
    unsigned short* w2T    = w1T + (size_t)4194304;          // [1024][4096]

    dim3 blk(256);
    const int MC = M * C;

    hipLaunchKernelGGL(cvt_bf16, dim3(MC / 1024), blk, 0, stream, expl, Ebf, MC);
    hipLaunchKernelGGL(cvt_bf16, dim3(MC / 1024), blk, 0, stream, x, Xbf, MC);
    hipLaunchKernelGGL(transpose_cvt, dim3(96, 32), blk, 0, stream, w_qkv, wqkvT, C, 3 * C);
    hipLaunchKernelGGL(transpose_cvt, dim3(32, 32), blk, 0, stream, w_proj, wprojT, C, C);
    hipLaunchKernelGGL(transpose_cvt, dim3(128, 32), blk, 0, stream, w1, w1T, C, F);
    hipLaunchKernelGGL(transpose_cvt, dim3(32, 128), blk, 0, stream, w2, w2T, F, C);

    // QK projection (explanation) -> bf16; V projection (x) -> bf16
    hipLaunchKernelGGL((gemm97<0,1>), dim3(64 * 16), blk, 0, stream, Ebf, wqkvT, (const float*)nullptr, (void*)QKbf, M, 2048, C, 2048);
    hipLaunchKernelGGL((gemm97<0,1>), dim3(64 * 8), blk, 0, stream, Xbf, wqkvT + (size_t)2048 * 1024, (const float*)nullptr, (void*)Vbf, M, 1024, C, 1024);

    // drofe: bf16 QK -> rotated bf16 Q (scaled), K
    hipLaunchKernelGGL(drofe_bf, dim3(M * 512 / 256), blk, 0, stream, QKbf, Qbf, Kbf, fb, demo, N);

    // attention -> bf16 O
    hipLaunchKernelGGL(attn_mfma, dim3(B * H * (N / 64)), blk, 0, stream, Qbf, Kbf, Vbf, Obf, B, H, N);

    // output projection
    hipLaunchKernelGGL((gemm97<1,0>), dim3(64 * 8), blk, 0, stream, Obf, wprojT, b_proj, (void*)Pb, M, 1024, C, 1024);

    // residual + LN1 (f32 + bf16)
    hipLaunchKernelGGL(ln_res_kernel, dim3(M), blk, 0, stream, x, Pb, gamma1, ln1_w, ln1_b, X1, X1bf, C);

    // MLP
    hipLaunchKernelGGL((gemm97<2,1>), dim3(64 * 32), blk, 0, stream, X1bf, w1T, b1, (void*)Hid, M, F, C, F);
    hipLaunchKernelGGL((gemm97<1,0>), dim3(64 * 8), blk, 0, stream, Hid, w2T, b2, (void*)H2, M, 1024, F, 1024);

    // residual + LN2 -> out
    hipLaunchKernelGGL(ln_res_kernel, dim3(M), blk, 0, stream, X1, H2, gamma2, ln2_w, ln2_b, out, (unsigned short*)nullptr, C);
}